// Round 1
// 175.725 us; speedup vs baseline: 1.3162x; 1.3162x over previous
//
#include <hip/hip_runtime.h>

// ResidualNetwork forward, MI355X (gfx950).
// Round 21: OCCUPANCY play. r20 held 24 weight fragments (96 regs) + acc in
// AGPRs -> ~200 total regs/lane -> 2.4 waves/SIMD (Occupancy 29.6%), and the
// r12-r19 "~300k busy cyc invariant" is latency exposure at that starvation
// level (~33 cyc effective per MFMA vs ~8 throughput). Change: stage the 24.6KB
// weight table in LDS (idle until now), ds_read_b128 each fragment at use
// (one read feeds both ILP chains; lane-contiguous, conflict-free). Live set
// drops to ~100 pure VGPRs, accvgpr traffic disappears, launch_bounds(256,4)
// -> >=4 waves/SIMD. Also: repack is now pack-then-relu (4 cvt_pkrtz +
// 4 v_pk_max_f16 = 8 VALU vs 12), bit-identical. asm-opaqued lane index stops
// LICM from hoisting the ds_reads back into registers.
// Gates: absmax 0 (bit-identical math); Occupancy ~2x; LDS_Block_Size 24576;
// FETCH ~24.8MB; WRITE 16384KB.

#define NPTS 4194304
#define NBLK 2048
#define NWAVES (NBLK * 4)           // 8192
#define NTILES (NPTS / 32)          // 131072
#define TPW (NTILES / NWAVES)       // 16 tiles per wave
#define NMM 24
#define ILP 2

typedef _Float16 h8 __attribute__((ext_vector_type(8)));
typedef float v16f __attribute__((ext_vector_type(16)));
typedef unsigned u4v __attribute__((ext_vector_type(4)));

__device__ __forceinline__ v16f mm(h8 a, h8 b, v16f c) {
    return __builtin_amdgcn_mfma_f32_32x32x16_f16(a, b, c, 0, 0, 0);
}
__device__ __forceinline__ unsigned pkrtz(float a, float b) {
    return __builtin_bit_cast(unsigned, __builtin_amdgcn_cvt_pkrtz(a, b));
}
// relu on packed f16: 4x v_pk_max_f16
__device__ __forceinline__ h8 relu8(h8 h) {
    h8 z = {0, 0, 0, 0, 0, 0, 0, 0};
    return __builtin_elementwise_max(h, z);
}
// pack+relu of D regs 0-7 (rows sigma(k)): B fragment, sigma order
__device__ __forceinline__ h8 rc_lo(v16f d) {
    u4v u;
    u.x = pkrtz(d[0], d[1]); u.y = pkrtz(d[2], d[3]);
    u.z = pkrtz(d[4], d[5]); u.w = pkrtz(d[6], d[7]);
    return relu8(__builtin_bit_cast(h8, u));
}
// pack+relu of D regs 8-15 (rows 16+sigma(k)): same sigma order
__device__ __forceinline__ h8 rc_hi(v16f d) {
    u4v u;
    u.x = pkrtz(d[8], d[9]);   u.y = pkrtz(d[10], d[11]);
    u.z = pkrtz(d[12], d[13]); u.w = pkrtz(d[14], d[15]);
    return relu8(__builtin_bit_cast(h8, u));
}

// ---------------- prepack: fused A fragments, sigma-permuted K ---------------
// q=0: layer0 (k rows: x0,x1,x2 @ rr<3, bias col rr==3, pass A[10][rr==3]=1)
// q=1: layer1 dense (w1,b1, pass row 10)
// q=2+2l: fused block A: m0-9=Wr1^T|rr==10:Br1 ; m16-25=Wr2^T|rr==10:Br2+Br3;
//         m26,rr==10: 1 (ones pass)
// q=3+2l: W3 shifted: m16-25 = Wr3^T (rows 0-15 and 26 zero -> srcC passthru)
// q=22: layer8 dense (w8,b8, pass row 10)   q=23: out row m=0 (w9,b9)
__global__ __launch_bounds__(64) void prepack(
    const float* __restrict__ w0, const float* __restrict__ b0,
    const float* __restrict__ w1, const float* __restrict__ b1,
    const float* __restrict__ Wr1, const float* __restrict__ Br1,
    const float* __restrict__ Wr2, const float* __restrict__ Br2,
    const float* __restrict__ Wr3, const float* __restrict__ Br3,
    const float* __restrict__ w8, const float* __restrict__ b8,
    const float* __restrict__ w9, const float* __restrict__ b9,
    h8* __restrict__ tab)
{
    const int q = blockIdx.x, l = threadIdx.x;
    const int m = l & 31, g = l >> 5;
    h8 v;
#pragma unroll
    for (int j = 0; j < 8; ++j) {
        const int rr = (j & 3) + 8 * (j >> 2) + 4 * g;  // sigma(k)
        float a = 0.0f;
        if (q == 0) {
            if (m < 10 && rr < 3)        a = w0[rr * 10 + m];
            else if (m < 10 && rr == 3)  a = b0[m];
            else if (m == 10 && rr == 3) a = 1.0f;
        } else if (q == 1 || q == 22) {
            const float* W = (q == 1) ? w1 : w8;
            const float* B = (q == 1) ? b1 : b8;
            if (m < 10 && rr < 10)        a = W[rr * 10 + m];
            else if (m < 10 && rr == 10)  a = B[m];
            else if (m == 10 && rr == 10) a = 1.0f;
        } else if (q == 23) {
            if (m == 0 && rr < 10)       a = w9[rr];
            else if (m == 0 && rr == 10) a = b9[0];
        } else if (((q - 2) & 1) == 0) {           // fused W1|W2 block
            const int bl = (q - 2) >> 1;
            if (m < 10) {
                if (rr < 10)       a = Wr1[bl * 100 + rr * 10 + m];
                else if (rr == 10) a = Br1[bl * 10 + m];
            } else if (m >= 16 && m < 26) {
                if (rr < 10)       a = Wr2[bl * 100 + rr * 10 + (m - 16)];
                else if (rr == 10) a = Br2[bl * 10 + (m - 16)] + Br3[bl * 10 + (m - 16)];
            } else if (m == 26 && rr == 10) {
                a = 1.0f;                          // ones pass for next layer
            }
        } else {                                   // W3, output rows 16-25
            const int bl = (q - 3) >> 1;
            if (m >= 16 && m < 26 && rr < 10)
                a = Wr3[bl * 100 + rr * 10 + (m - 16)];
        }
        v[j] = (_Float16)a;
    }
    tab[q * 64 + l] = v;
}

// ---------------- main kernel: fused 24-MFMA chain, LDS weights, ILP=2 -------
__global__ __launch_bounds__(256, 4) void resnet_fwd(
    const float* __restrict__ x,
    const h8* __restrict__ tab,
    float* __restrict__ out)
{
    // stage the 24 A-fragment planes (24*64*16B = 24.6 KB) once per block
    __shared__ h8 sA[NMM * 64];
    for (int i = threadIdx.x; i < NMM * 64; i += 256) sA[i] = tab[i];
    __syncthreads();

    const int lane = threadIdx.x & 63;
    const int wv = blockIdx.x * 4 + (threadIdx.x >> 6);
    const int col = lane & 31;
    const bool lo = lane < 32;

    // resident zero srcC
    v16f zero;
#pragma unroll
    for (int j = 0; j < 16; ++j) zero[j] = 0.0f;
    asm volatile("" : "+v"(zero));

    const long tile0 = (long)wv * TPW;

    for (int t = 0; t < TPW; t += ILP) {
        // opaque lane index: stops LICM from hoisting all 24 ds_reads out of
        // the t-loop (which would re-inflate the live set to r20 levels).
        int ln = lane;
        asm volatile("" : "+v"(ln));
        const h8* wp = &sA[ln];

        long base[ILP];
        h8 hh[ILP];

        // layer-0 B: lanes 0-31 carry (x0,x1,x2,1) in k-rows 0-3; rest zero
#pragma unroll
        for (int c = 0; c < ILP; ++c) {
            base[c] = (tile0 + t + c) * 32;
            float a0 = 0.f, a1 = 0.f, a2 = 0.f, a3 = 0.f;
            if (lo) {
                const float* p = x + (base[c] + col) * 3;
                a0 = p[0]; a1 = p[1]; a2 = p[2]; a3 = 1.0f;
            }
            u4v u;
            u.x = pkrtz(a0, a1); u.y = pkrtz(a2, a3); u.z = 0u; u.w = 0u;
            hh[c] = __builtin_bit_cast(h8, u);
        }

        // layer 0, layer 1 (one ds_read feeds both ILP chains)
        {
            h8 a0 = wp[0 * 64];
#pragma unroll
            for (int c = 0; c < ILP; ++c) hh[c] = rc_lo(mm(a0, hh[c], zero));
            h8 a1 = wp[1 * 64];
#pragma unroll
            for (int c = 0; c < ILP; ++c) hh[c] = rc_lo(mm(a1, hh[c], zero));
        }

        // residual blocks: 2 MFMA each (fused W1|W2, then W3 onto rows 16-26)
#pragma unroll
        for (int bl = 0; bl < 10; ++bl) {
            h8 a12 = wp[(2 + 2 * bl) * 64];
            h8 a3  = wp[(3 + 2 * bl) * 64];
            v16f d12[ILP];
#pragma unroll
            for (int c = 0; c < ILP; ++c) d12[c] = mm(a12, hh[c], zero);
#pragma unroll
            for (int c = 0; c < ILP; ++c) {
                h8 t1 = rc_lo(d12[c]);
                d12[c] = mm(a3, t1, d12[c]);
            }
#pragma unroll
            for (int c = 0; c < ILP; ++c) hh[c] = rc_hi(d12[c]);
        }

        // layer 8
        {
            h8 a8 = wp[22 * 64];
#pragma unroll
            for (int c = 0; c < ILP; ++c) hh[c] = rc_lo(mm(a8, hh[c], zero));
        }

        // output layer: D row 0 (lanes 0-31, reg 0) = result for 32 points
        {
            h8 a9 = wp[23 * 64];
#pragma unroll
            for (int c = 0; c < ILP; ++c) {
                v16f d = mm(a9, hh[c], zero);
                if (lo) out[base[c] + col] = d[0];
            }
        }
    }
}

extern "C" void kernel_launch(void* const* d_in, const int* in_sizes, int n_in,
                              void* d_out, int out_size, void* d_ws, size_t ws_size,
                              hipStream_t stream)
{
    const float* x   = (const float*)d_in[0];
    const float* w0  = (const float*)d_in[1];
    const float* b0  = (const float*)d_in[2];
    const float* w1  = (const float*)d_in[3];
    const float* b1  = (const float*)d_in[4];
    const float* Wr1 = (const float*)d_in[5];
    const float* Br1 = (const float*)d_in[6];
    const float* Wr2 = (const float*)d_in[7];
    const float* Br2 = (const float*)d_in[8];
    const float* Wr3 = (const float*)d_in[9];
    const float* Br3 = (const float*)d_in[10];
    const float* w8  = (const float*)d_in[11];
    const float* b8  = (const float*)d_in[12];
    const float* w9  = (const float*)d_in[13];
    const float* b9  = (const float*)d_in[14];
    float* out = (float*)d_out;
    h8* tab = (h8*)d_ws;   // 24 * 64 * 16B = 24.6 KB scratch

    hipLaunchKernelGGL(prepack, dim3(NMM), dim3(64), 0, stream,
                       w0, b0, w1, b1, Wr1, Br1, Wr2, Br2, Wr3, Br3,
                       w8, b8, w9, b9, tab);

    hipLaunchKernelGGL(resnet_fwd, dim3(NBLK), dim3(256), 0, stream,
                       x, (const h8*)tab, out);
}

// Round 2
// 173.528 us; speedup vs baseline: 1.3329x; 1.0127x over previous
//
#include <hip/hip_runtime.h>

// ResidualNetwork forward, MI355X (gfx950).
// Round 22: ILP 2->4. r21 (LDS weight table) confirmed the occupancy theory:
// 144.8->83.0us, Occ 29.6->46%, VGPR 76(+AGPR)->40. Both pipes still half-idle
// (Mfma 54 / VALU 63) because chains/SIMD = 3.7 waves x ILP2 = 7.4 vs ~50cyc
// step latency needing >=12-16. VGPR=40 of 128 cap -> double ILP in-place:
// 16 chains/SIMD, est ~110 VGPR (d12[4]=64 + hh[4]=16 + zero=16 + addr), and
// per-chain LDS traffic halves (24 ds_read_b128 now feed 4 chains) keeping the
// LDS pipe (~31us/CU at ILP2 rates) off the critical path. launch_bounds stays
// (256,4). ln asm-opaque guard stays: with 4 t-iterations LICM would hoist all
// 24 fragments into regs and recreate r20's AGPR blowup.
// Gates: absmax 0; VGPR ~105-120 no scratch; Mfma ~75; VALU ~80; main ~58us.

#define NPTS 4194304
#define NBLK 2048
#define NWAVES (NBLK * 4)           // 8192
#define NTILES (NPTS / 32)          // 131072
#define TPW (NTILES / NWAVES)       // 16 tiles per wave
#define NMM 24
#define ILP 4

typedef _Float16 h8 __attribute__((ext_vector_type(8)));
typedef float v16f __attribute__((ext_vector_type(16)));
typedef unsigned u4v __attribute__((ext_vector_type(4)));

__device__ __forceinline__ v16f mm(h8 a, h8 b, v16f c) {
    return __builtin_amdgcn_mfma_f32_32x32x16_f16(a, b, c, 0, 0, 0);
}
__device__ __forceinline__ unsigned pkrtz(float a, float b) {
    return __builtin_bit_cast(unsigned, __builtin_amdgcn_cvt_pkrtz(a, b));
}
// relu on packed f16: 4x v_pk_max_f16
__device__ __forceinline__ h8 relu8(h8 h) {
    h8 z = {0, 0, 0, 0, 0, 0, 0, 0};
    return __builtin_elementwise_max(h, z);
}
// pack+relu of D regs 0-7 (rows sigma(k)): B fragment, sigma order
__device__ __forceinline__ h8 rc_lo(v16f d) {
    u4v u;
    u.x = pkrtz(d[0], d[1]); u.y = pkrtz(d[2], d[3]);
    u.z = pkrtz(d[4], d[5]); u.w = pkrtz(d[6], d[7]);
    return relu8(__builtin_bit_cast(h8, u));
}
// pack+relu of D regs 8-15 (rows 16+sigma(k)): same sigma order
__device__ __forceinline__ h8 rc_hi(v16f d) {
    u4v u;
    u.x = pkrtz(d[8], d[9]);   u.y = pkrtz(d[10], d[11]);
    u.z = pkrtz(d[12], d[13]); u.w = pkrtz(d[14], d[15]);
    return relu8(__builtin_bit_cast(h8, u));
}

// ---------------- prepack: fused A fragments, sigma-permuted K ---------------
// q=0: layer0 (k rows: x0,x1,x2 @ rr<3, bias col rr==3, pass A[10][rr==3]=1)
// q=1: layer1 dense (w1,b1, pass row 10)
// q=2+2l: fused block A: m0-9=Wr1^T|rr==10:Br1 ; m16-25=Wr2^T|rr==10:Br2+Br3;
//         m26,rr==10: 1 (ones pass)
// q=3+2l: W3 shifted: m16-25 = Wr3^T (rows 0-15 and 26 zero -> srcC passthru)
// q=22: layer8 dense (w8,b8, pass row 10)   q=23: out row m=0 (w9,b9)
__global__ __launch_bounds__(64) void prepack(
    const float* __restrict__ w0, const float* __restrict__ b0,
    const float* __restrict__ w1, const float* __restrict__ b1,
    const float* __restrict__ Wr1, const float* __restrict__ Br1,
    const float* __restrict__ Wr2, const float* __restrict__ Br2,
    const float* __restrict__ Wr3, const float* __restrict__ Br3,
    const float* __restrict__ w8, const float* __restrict__ b8,
    const float* __restrict__ w9, const float* __restrict__ b9,
    h8* __restrict__ tab)
{
    const int q = blockIdx.x, l = threadIdx.x;
    const int m = l & 31, g = l >> 5;
    h8 v;
#pragma unroll
    for (int j = 0; j < 8; ++j) {
        const int rr = (j & 3) + 8 * (j >> 2) + 4 * g;  // sigma(k)
        float a = 0.0f;
        if (q == 0) {
            if (m < 10 && rr < 3)        a = w0[rr * 10 + m];
            else if (m < 10 && rr == 3)  a = b0[m];
            else if (m == 10 && rr == 3) a = 1.0f;
        } else if (q == 1 || q == 22) {
            const float* W = (q == 1) ? w1 : w8;
            const float* B = (q == 1) ? b1 : b8;
            if (m < 10 && rr < 10)        a = W[rr * 10 + m];
            else if (m < 10 && rr == 10)  a = B[m];
            else if (m == 10 && rr == 10) a = 1.0f;
        } else if (q == 23) {
            if (m == 0 && rr < 10)       a = w9[rr];
            else if (m == 0 && rr == 10) a = b9[0];
        } else if (((q - 2) & 1) == 0) {           // fused W1|W2 block
            const int bl = (q - 2) >> 1;
            if (m < 10) {
                if (rr < 10)       a = Wr1[bl * 100 + rr * 10 + m];
                else if (rr == 10) a = Br1[bl * 10 + m];
            } else if (m >= 16 && m < 26) {
                if (rr < 10)       a = Wr2[bl * 100 + rr * 10 + (m - 16)];
                else if (rr == 10) a = Br2[bl * 10 + (m - 16)] + Br3[bl * 10 + (m - 16)];
            } else if (m == 26 && rr == 10) {
                a = 1.0f;                          // ones pass for next layer
            }
        } else {                                   // W3, output rows 16-25
            const int bl = (q - 3) >> 1;
            if (m >= 16 && m < 26 && rr < 10)
                a = Wr3[bl * 100 + rr * 10 + (m - 16)];
        }
        v[j] = (_Float16)a;
    }
    tab[q * 64 + l] = v;
}

// ---------------- main kernel: fused 24-MFMA chain, LDS weights, ILP=4 -------
__global__ __launch_bounds__(256, 4) void resnet_fwd(
    const float* __restrict__ x,
    const h8* __restrict__ tab,
    float* __restrict__ out)
{
    // stage the 24 A-fragment planes (24*64*16B = 24.6 KB) once per block
    __shared__ h8 sA[NMM * 64];
    for (int i = threadIdx.x; i < NMM * 64; i += 256) sA[i] = tab[i];
    __syncthreads();

    const int lane = threadIdx.x & 63;
    const int wv = blockIdx.x * 4 + (threadIdx.x >> 6);
    const int col = lane & 31;
    const bool lo = lane < 32;

    // resident zero srcC
    v16f zero;
#pragma unroll
    for (int j = 0; j < 16; ++j) zero[j] = 0.0f;
    asm volatile("" : "+v"(zero));

    const long tile0 = (long)wv * TPW;

    for (int t = 0; t < TPW; t += ILP) {
        // opaque lane index: stops LICM from hoisting all 24 ds_reads out of
        // the t-loop (which would re-inflate the live set to r20 levels).
        int ln = lane;
        asm volatile("" : "+v"(ln));
        const h8* wp = &sA[ln];

        long base[ILP];
        h8 hh[ILP];

        // layer-0 B: lanes 0-31 carry (x0,x1,x2,1) in k-rows 0-3; rest zero
#pragma unroll
        for (int c = 0; c < ILP; ++c) {
            base[c] = (tile0 + t + c) * 32;
            float a0 = 0.f, a1 = 0.f, a2 = 0.f, a3 = 0.f;
            if (lo) {
                const float* p = x + (base[c] + col) * 3;
                a0 = p[0]; a1 = p[1]; a2 = p[2]; a3 = 1.0f;
            }
            u4v u;
            u.x = pkrtz(a0, a1); u.y = pkrtz(a2, a3); u.z = 0u; u.w = 0u;
            hh[c] = __builtin_bit_cast(h8, u);
        }

        // layer 0, layer 1 (one ds_read feeds all ILP chains)
        {
            h8 a0 = wp[0 * 64];
#pragma unroll
            for (int c = 0; c < ILP; ++c) hh[c] = rc_lo(mm(a0, hh[c], zero));
            h8 a1 = wp[1 * 64];
#pragma unroll
            for (int c = 0; c < ILP; ++c) hh[c] = rc_lo(mm(a1, hh[c], zero));
        }

        // residual blocks: 2 MFMA each (fused W1|W2, then W3 onto rows 16-26)
#pragma unroll
        for (int bl = 0; bl < 10; ++bl) {
            h8 a12 = wp[(2 + 2 * bl) * 64];
            h8 a3  = wp[(3 + 2 * bl) * 64];
            v16f d12[ILP];
#pragma unroll
            for (int c = 0; c < ILP; ++c) d12[c] = mm(a12, hh[c], zero);
#pragma unroll
            for (int c = 0; c < ILP; ++c) {
                h8 t1 = rc_lo(d12[c]);
                d12[c] = mm(a3, t1, d12[c]);
            }
#pragma unroll
            for (int c = 0; c < ILP; ++c) hh[c] = rc_hi(d12[c]);
        }

        // layer 8
        {
            h8 a8 = wp[22 * 64];
#pragma unroll
            for (int c = 0; c < ILP; ++c) hh[c] = rc_lo(mm(a8, hh[c], zero));
        }

        // output layer: D row 0 (lanes 0-31, reg 0) = result for 32 points
        {
            h8 a9 = wp[23 * 64];
#pragma unroll
            for (int c = 0; c < ILP; ++c) {
                v16f d = mm(a9, hh[c], zero);
                if (lo) out[base[c] + col] = d[0];
            }
        }
    }
}

extern "C" void kernel_launch(void* const* d_in, const int* in_sizes, int n_in,
                              void* d_out, int out_size, void* d_ws, size_t ws_size,
                              hipStream_t stream)
{
    const float* x   = (const float*)d_in[0];
    const float* w0  = (const float*)d_in[1];
    const float* b0  = (const float*)d_in[2];
    const float* w1  = (const float*)d_in[3];
    const float* b1  = (const float*)d_in[4];
    const float* Wr1 = (const float*)d_in[5];
    const float* Br1 = (const float*)d_in[6];
    const float* Wr2 = (const float*)d_in[7];
    const float* Br2 = (const float*)d_in[8];
    const float* Wr3 = (const float*)d_in[9];
    const float* Br3 = (const float*)d_in[10];
    const float* w8  = (const float*)d_in[11];
    const float* b8  = (const float*)d_in[12];
    const float* w9  = (const float*)d_in[13];
    const float* b9  = (const float*)d_in[14];
    float* out = (float*)d_out;
    h8* tab = (h8*)d_ws;   // 24 * 64 * 16B = 24.6 KB scratch

    hipLaunchKernelGGL(prepack, dim3(NMM), dim3(64), 0, stream,
                       w0, b0, w1, b1, Wr1, Br1, Wr2, Br2, Wr3, Br3,
                       w8, b8, w9, b9, tab);

    hipLaunchKernelGGL(resnet_fwd, dim3(NBLK), dim3(256), 0, stream,
                       x, (const h8*)tab, out);
}